// Round 1
// baseline (461.042 us; speedup 1.0000x reference)
//
#include <hip/hip_runtime.h>
#include <float.h>

// Problem constants (from reference setup_inputs)
#define B_SZ 2
#define N_SZ 16384                  // N == M
#define E_SZ 49152

#define TPB 512
#define WAVES (TPB / 64)            // 8
#define ROWS_PER_BLOCK 128          // 2 row-pairs x 64 rows; 4 col-groups
#define CHUNK 1024                  // target points per LDS chunk
#define NCHUNK (N_SZ / CHUNK)       // 16
#define TILES_PER_CHUNK (CHUNK / 32) // 32
#define TILES_PER_CG (TILES_PER_CHUNK / 4) // 8 col-tiles per col-group

#define CH_BLOCKS_PER_DIR (B_SZ * N_SZ / ROWS_PER_BLOCK)  // 256
#define CH_BLOCKS (2 * CH_BLOCKS_PER_DIR)                 // 512
#define EDGE_BLOCKS (B_SZ * E_SZ / TPB)                   // 192

// frag workspace: per dir, per batch: plane0 [16384 x 16B] then plane1
#define PLANE_BYTES (N_SZ * 16)                 // 256 KB
#define BATCH_FRAG_BYTES (2 * PLANE_BYTES)      // 512 KB
#define DIR_FRAG_BYTES (B_SZ * BATCH_FRAG_BYTES) // 1 MB
#define SUMS_OFF (2 * DIR_FRAG_BYTES)           // 2 MB

typedef short short8 __attribute__((ext_vector_type(8)));
typedef float f32x16 __attribute__((ext_vector_type(16)));

// ---- bf16 bit helpers (RNE); inputs are finite Gaussians ----
__device__ inline short f2bf(float f) {
    unsigned u = __float_as_uint(f);
    unsigned r = (u + 0x7fffu + ((u >> 16) & 1u)) >> 16;
    return (short)r;
}
__device__ inline float bf2f(short s) {
    return __uint_as_float(((unsigned)(unsigned short)s) << 16);
}

// ---- async global->LDS 16B per lane (CK-style addrspace casts) ----
typedef __attribute__((address_space(1))) const unsigned int g_u32;
typedef __attribute__((address_space(3))) unsigned int l_u32;
__device__ inline void gload_lds16(const void* g, void* l) {
    __builtin_amdgcn_global_load_lds((g_u32*)g, (l_u32*)l, 16, 0, 0);
}

// ---- prep: convert every point to B-operand fragments + zero sums ----
// B-rep per point t (search-set role):
//   plane0 (k0-7):  {thx,thy,thz, thx,thy,thz, 1, 1}
//   plane1 (k8-15): {tlx,tly,tlz, t2h,t2l, 0,0,0}
// idx 0..32767: tgt points -> dir0 buffer; 32768..65535: pred -> dir1 buffer.
__global__ __launch_bounds__(TPB) void prep(const float* __restrict__ pred,
                                            const float* __restrict__ tgt,
                                            char* __restrict__ ws) {
    int idx = blockIdx.x * TPB + threadIdx.x;       // 0..65535
    double* sums = (double*)(ws + SUMS_OFF);
    if (blockIdx.x == 0 && threadIdx.x < 6) sums[threadIdx.x] = 0.0;

    const bool isTgt = idx < B_SZ * N_SZ;
    int row = isTgt ? idx : idx - B_SZ * N_SZ;      // 0..32767
    int batch = row >> 14, pt = row & (N_SZ - 1);
    const float* src = (isTgt ? tgt : pred) + (size_t)row * 3;
    char* base = ws + (isTgt ? 0 : DIR_FRAG_BYTES) + (size_t)batch * BATCH_FRAG_BYTES;

    float tx = src[0], ty = src[1], tz = src[2];
    short hx = f2bf(tx), hy = f2bf(ty), hz = f2bf(tz);
    short lx = f2bf(tx - bf2f(hx)), ly = f2bf(ty - bf2f(hy)), lz = f2bf(tz - bf2f(hz));
    float t2 = fmaf(tx, tx, fmaf(ty, ty, tz * tz));
    short t2h = f2bf(t2), t2l = f2bf(t2 - bf2f(t2h));
    const short one = 0x3f80;

    *(short8*)(base + (size_t)pt * 16) = (short8){hx, hy, hz, hx, hy, hz, one, one};
    *(short8*)(base + PLANE_BYTES + (size_t)pt * 16) =
        (short8){lx, ly, lz, t2h, t2l, 0, 0, 0};
}

// ---- main: chamfer (both directions) + edge ----
// d^2 = (-2p).t + p^2 + t^2 via K=13 bf16 hi/lo split in ONE 32x32x16 MFMA.
// A lane: m=lane&31, k=(lane>>5)*8+j:
//   half0 (k0-7):  {ahx,ahy,ahz, alx,aly,alz, p2h,p2l}   (a = -2p)
//   half1 (k8-15): {ahx,ahy,ahz, 1, 1, 0,0,0}
// C/D (verified m74/m101): col=lane&31, row=(reg&3)+8*(reg>>2)+4*(lane>>5).
//
// R7 restructure (latency/LDS-bound diagnosis):
//  - each wave owns TWO 32-row A-tiles -> one ds_read_b128 feeds 2 MFMAs
//    (halves LDS read traffic) and min3-pairs the fminf reduction.
//  - 512 chamfer blocks of 128 rows: 8 waves = 2 row-pairs x 4 col-groups;
//    col-groups merged via per-row LDS atomicMin. 2 blocks/CU -> 4 waves/SIMD.
//  - global_load_lds staging (no reg round-trip), double-buffered.
// NOTE: fminf chains only (NO inline-asm v_min3: MFMA->VALU hazard, see R5->R6).
__global__ __launch_bounds__(TPB, 4) void main_kernel(
    const float* __restrict__ pred, const float* __restrict__ tgt,
    const int* __restrict__ edges, char* __restrict__ ws)
{
    __shared__ __align__(16) char sB[2][2 * CHUNK * 16];   // 2 x 32 KB
    __shared__ float wred[WAVES], wred2[WAVES];
    __shared__ int rowMin[ROWS_PER_BLOCK];
    double* sums = (double*)(ws + SUMS_OFF);
    const int lane = threadIdx.x & 63;
    const int wv = threadIdx.x >> 6;
    const int t = threadIdx.x;

    if (blockIdx.x < CH_BLOCKS) {
        const int dir = blockIdx.x >> 8;          // 0: rows=pred, search tgt
        const int xb = blockIdx.x & 255;
        const int batch = xb >> 7;
        const int rowInB = (xb & 127) * ROWS_PER_BLOCK;
        const float* P = dir ? tgt : pred;
        const char* fragBase = ws + (size_t)dir * DIR_FRAG_BYTES
                                  + (size_t)batch * BATCH_FRAG_BYTES;
        const int bl = lane & 31;
        const int half = lane >> 5;
        const int rp = wv & 1;                    // row-pair: tiles 2rp,2rp+1
        const int cg = wv >> 1;                   // col-group: tiles [cg*8,cg*8+8)

        auto stage = [&](int c, int buf) {
            const char* p0 = fragBase + (size_t)c * (CHUNK * 16);
            const char* p1 = fragBase + PLANE_BYTES + (size_t)c * (CHUNK * 16);
            char* d = sB[buf];
            gload_lds16(p0 + (size_t)t * 16,         d + (size_t)t * 16);
            gload_lds16(p0 + (size_t)(t + TPB) * 16, d + (size_t)(t + TPB) * 16);
            gload_lds16(p1 + (size_t)t * 16,         d + (size_t)(t + 2 * TPB) * 16);
            gload_lds16(p1 + (size_t)(t + TPB) * 16, d + (size_t)(t + 3 * TPB) * 16);
        };
        stage(0, 0);
        if (t < ROWS_PER_BLOCK) rowMin[t] = 0x7f7fffff;   // FLT_MAX bits

        // ---- A fragments for the wave's two row tiles ----
        const short one = 0x3f80;
        short8 af[2];
        #pragma unroll
        for (int j = 0; j < 2; j++) {
            int r = batch * N_SZ + rowInB + rp * 64 + j * 32 + bl;
            const float* p = P + (size_t)r * 3;
            float px = p[0], py = p[1], pz = p[2];
            float ax = -2.f * px, ay = -2.f * py, az = -2.f * pz;
            short ahx = f2bf(ax), ahy = f2bf(ay), ahz = f2bf(az);
            short alx = f2bf(ax - bf2f(ahx)), aly = f2bf(ay - bf2f(ahy)),
                  alz = f2bf(az - bf2f(ahz));
            float p2 = fmaf(px, px, fmaf(py, py, pz * pz));
            short p2h = f2bf(p2), p2l = f2bf(p2 - bf2f(p2h));
            af[j] = half == 0
                ? (short8){ahx, ahy, ahz, alx, aly, alz, p2h, p2l}
                : (short8){ahx, ahy, ahz, one, one, 0, 0, 0};
        }

        float acc0[16], acc1[16];
        #pragma unroll
        for (int e = 0; e < 16; e++) { acc0[e] = FLT_MAX; acc1[e] = FLT_MAX; }
        const f32x16 zc = {0.f, 0.f, 0.f, 0.f, 0.f, 0.f, 0.f, 0.f,
                           0.f, 0.f, 0.f, 0.f, 0.f, 0.f, 0.f, 0.f};

        __syncthreads();

        for (int c = 0; c < NCHUNK; c++) {
            int buf = c & 1;
            if (c + 1 < NCHUNK) stage(c + 1, buf ^ 1);   // async, drains at barrier
            const char* bp = sB[buf] + half * (CHUNK * 16)
                           + (size_t)(cg * TILES_PER_CG * 32 + bl) * 16;
            #pragma unroll
            for (int mt = 0; mt < TILES_PER_CG; mt += 2) {
                short8 b0 = *(const short8*)(bp + (mt * 32) * 16);
                short8 b1 = *(const short8*)(bp + (mt * 32 + 32) * 16);
                f32x16 r00 = __builtin_amdgcn_mfma_f32_32x32x16_bf16(af[0], b0, zc, 0, 0, 0);
                f32x16 r01 = __builtin_amdgcn_mfma_f32_32x32x16_bf16(af[0], b1, zc, 0, 0, 0);
                #pragma unroll
                for (int e = 0; e < 16; e++)
                    acc0[e] = fminf(fminf(r00[e], r01[e]), acc0[e]);   // v_min3-able
                f32x16 r10 = __builtin_amdgcn_mfma_f32_32x32x16_bf16(af[1], b0, zc, 0, 0, 0);
                f32x16 r11 = __builtin_amdgcn_mfma_f32_32x32x16_bf16(af[1], b1, zc, 0, 0, 0);
                #pragma unroll
                for (int e = 0; e < 16; e++)
                    acc1[e] = fminf(fminf(r10[e], r11[e]), acc1[e]);
            }
            __syncthreads();
        }

        // ---- fold 32 col-lanes, publish per-row minima via LDS atomicMin ----
        #pragma unroll
        for (int j = 0; j < 2; j++) {
            #pragma unroll
            for (int e = 0; e < 16; e++) {
                float v = (j == 0) ? acc0[e] : acc1[e];
                v = fminf(v, __shfl_xor(v, 1));
                v = fminf(v, __shfl_xor(v, 2));
                v = fminf(v, __shfl_xor(v, 4));
                v = fminf(v, __shfl_xor(v, 8));
                v = fminf(v, __shfl_xor(v, 16));
                if (bl == 0) {
                    int row = rp * 64 + j * 32 + (e & 3) + 8 * (e >> 2) + 4 * half;
                    atomicMin(&rowMin[row], __float_as_int(fmaxf(v, 0.f)));
                }
            }
        }
        __syncthreads();

        // ---- sqrt + block sum (rows live in threads 0..127 = waves 0,1) ----
        if (t < ROWS_PER_BLOCK) {
            float s = sqrtf(__int_as_float(rowMin[t]));
            #pragma unroll
            for (int o = 32; o > 0; o >>= 1) s += __shfl_down(s, o, 64);
            if (lane == 0) wred[wv] = s;
        }
        __syncthreads();
        if (t == 0) atomicAdd(&sums[dir], (double)(wred[0] + wred[1]));
    } else {
        // ---- edge loss (int32 edges per harness convention) ----
        int idx = (blockIdx.x - CH_BLOCKS) * TPB + threadIdx.x;  // 0..98303
        int b = idx >= E_SZ;                        // block-uniform (96 blocks/b)
        int e = idx - b * E_SZ;
        int2 ee = ((const int2*)edges)[e];
        const float* p0 = pred + ((size_t)b * N_SZ + (size_t)ee.x) * 3;
        const float* p1 = pred + ((size_t)b * N_SZ + (size_t)ee.y) * 3;
        float dx = p0[0] - p1[0], dy = p0[1] - p1[1], dz = p0[2] - p1[2];
        float len = sqrtf(dx * dx + dy * dy + dz * dz);
        float s = len, q = len * len;
        for (int o = 32; o > 0; o >>= 1) {
            s += __shfl_down(s, o, 64);
            q += __shfl_down(q, o, 64);
        }
        if (lane == 0) { wred[wv] = s; wred2[wv] = q; }
        __syncthreads();
        if (threadIdx.x == 0) {
            float ts = 0.f, tq = 0.f;
            #pragma unroll
            for (int w = 0; w < WAVES; w++) { ts += wred[w]; tq += wred2[w]; }
            atomicAdd(&sums[2 + 2 * b], (double)ts);
            atomicAdd(&sums[3 + 2 * b], (double)tq);
        }
    }
}

// ---- combine to the 3 outputs ----
__global__ void final_kernel(const char* __restrict__ ws, float* __restrict__ out) {
    const double* sums = (const double*)(ws + SUMS_OFF);
    double c = sums[0] / (double)(B_SZ * N_SZ) + sums[1] / (double)(B_SZ * N_SZ);
    double e = 0.0;
    #pragma unroll
    for (int b = 0; b < B_SZ; b++) {
        double s = sums[2 + 2 * b], q = sums[3 + 2 * b];
        e += (q - s * s / (double)E_SZ) / (double)(E_SZ - 1);
    }
    e *= (1.0 / B_SZ);
    double tot = 1.0 * c + 0.1 * e;
    out[0] = (float)tot;
    out[1] = (float)c;
    out[2] = (float)e;
}

extern "C" void kernel_launch(void* const* d_in, const int* in_sizes, int n_in,
                              void* d_out, int out_size, void* d_ws, size_t ws_size,
                              hipStream_t stream) {
    const float* pred = (const float*)d_in[0];       // (B, N, 3) fp32
    const float* tgt  = (const float*)d_in[1];       // (B, M, 3) fp32
    const int* edges  = (const int*)d_in[2];         // (E, 2) int32 (harness-converted)
    float* out = (float*)d_out;
    char* ws = (char*)d_ws;                          // needs 2 MB + 48 B

    // 1) convert points to MFMA B-fragments + zero sums
    prep<<<dim3((2 * B_SZ * N_SZ) / TPB), TPB, 0, stream>>>(pred, tgt, ws);

    // 2) chamfer (512 blocks, both dirs, complete row-mins) + edge (192 blocks)
    main_kernel<<<dim3(CH_BLOCKS + EDGE_BLOCKS), TPB, 0, stream>>>(
        pred, tgt, edges, ws);

    // 3) combine
    final_kernel<<<dim3(1), dim3(1), 0, stream>>>(ws, out);
}

// Round 2
// 103.495 us; speedup vs baseline: 4.4547x; 4.4547x over previous
//
#include <hip/hip_runtime.h>
#include <float.h>

// Problem constants (from reference setup_inputs)
#define B_SZ 2
#define N_SZ 16384                  // N == M
#define E_SZ 49152

#define TPB 512
#define WAVES (TPB / 64)            // 8
#define ROWS_PER_BLOCK 128          // 2 row-pairs x 64 rows; 4 col-groups
#define CHUNK 1024                  // target points per LDS chunk
#define NCHUNK (N_SZ / CHUNK)       // 16
#define TILES_PER_CHUNK (CHUNK / 32) // 32
#define TILES_PER_CG (TILES_PER_CHUNK / 4) // 8 col-tiles per col-group

#define CH_BLOCKS_PER_DIR (B_SZ * N_SZ / ROWS_PER_BLOCK)  // 256
#define CH_BLOCKS (2 * CH_BLOCKS_PER_DIR)                 // 512
#define EDGE_BLOCKS (B_SZ * E_SZ / TPB)                   // 192

// frag workspace: per dir, per batch: plane0 [16384 x 16B] then plane1
#define PLANE_BYTES (N_SZ * 16)                 // 256 KB
#define BATCH_FRAG_BYTES (2 * PLANE_BYTES)      // 512 KB
#define DIR_FRAG_BYTES (B_SZ * BATCH_FRAG_BYTES) // 1 MB
#define SUMS_OFF (2 * DIR_FRAG_BYTES)           // 2 MB

typedef short short8 __attribute__((ext_vector_type(8)));
typedef float f32x16 __attribute__((ext_vector_type(16)));

// ---- bf16 bit helpers (RNE); inputs are finite Gaussians ----
__device__ inline short f2bf(float f) {
    unsigned u = __float_as_uint(f);
    unsigned r = (u + 0x7fffu + ((u >> 16) & 1u)) >> 16;
    return (short)r;
}
__device__ inline float bf2f(short s) {
    return __uint_as_float(((unsigned)(unsigned short)s) << 16);
}

// ---- async global->LDS 16B per lane (CK-style addrspace casts) ----
typedef __attribute__((address_space(1))) const unsigned int g_u32;
typedef __attribute__((address_space(3))) unsigned int l_u32;
__device__ inline void gload_lds16(const void* g, void* l) {
    __builtin_amdgcn_global_load_lds((g_u32*)g, (l_u32*)l, 16, 0, 0);
}

// ---- prep: convert every point to B-operand fragments + zero sums ----
// B-rep per point t (search-set role):
//   plane0 (k0-7):  {thx,thy,thz, thx,thy,thz, 1, 1}
//   plane1 (k8-15): {tlx,tly,tlz, t2h,t2l, 0,0,0}
// idx 0..32767: tgt points -> dir0 buffer; 32768..65535: pred -> dir1 buffer.
__global__ __launch_bounds__(TPB) void prep(const float* __restrict__ pred,
                                            const float* __restrict__ tgt,
                                            char* __restrict__ ws) {
    int idx = blockIdx.x * TPB + threadIdx.x;       // 0..65535
    double* sums = (double*)(ws + SUMS_OFF);
    if (blockIdx.x == 0 && threadIdx.x < 6) sums[threadIdx.x] = 0.0;

    const bool isTgt = idx < B_SZ * N_SZ;
    int row = isTgt ? idx : idx - B_SZ * N_SZ;      // 0..32767
    int batch = row >> 14, pt = row & (N_SZ - 1);
    const float* src = (isTgt ? tgt : pred) + (size_t)row * 3;
    char* base = ws + (isTgt ? 0 : DIR_FRAG_BYTES) + (size_t)batch * BATCH_FRAG_BYTES;

    float tx = src[0], ty = src[1], tz = src[2];
    short hx = f2bf(tx), hy = f2bf(ty), hz = f2bf(tz);
    short lx = f2bf(tx - bf2f(hx)), ly = f2bf(ty - bf2f(hy)), lz = f2bf(tz - bf2f(hz));
    float t2 = fmaf(tx, tx, fmaf(ty, ty, tz * tz));
    short t2h = f2bf(t2), t2l = f2bf(t2 - bf2f(t2h));
    const short one = 0x3f80;

    *(short8*)(base + (size_t)pt * 16) = (short8){hx, hy, hz, hx, hy, hz, one, one};
    *(short8*)(base + PLANE_BYTES + (size_t)pt * 16) =
        (short8){lx, ly, lz, t2h, t2l, 0, 0, 0};
}

// ---- main: chamfer (both directions) + edge ----
// d^2 = (-2p).t + p^2 + t^2 via K=13 bf16 hi/lo split in ONE 32x32x16 MFMA.
// A lane: m=lane&31, k=(lane>>5)*8+j:
//   half0 (k0-7):  {ahx,ahy,ahz, alx,aly,alz, p2h,p2l}   (a = -2p)
//   half1 (k8-15): {ahx,ahy,ahz, 1, 1, 0,0,0}
// C/D (verified m74/m101): col=lane&31, row=(reg&3)+8*(reg>>2)+4*(lane>>5).
//
// R8 fix of R7's scratch-spill disaster (WRITE_SIZE 332 MB, VGPR capped at 64):
//  - only TWO f32x16 MFMA results live at a time: reduce acc0 before issuing
//    the af[1] MFMAs so the result registers are reused (~96-110 unified regs,
//    fits the 128/wave cap that __launch_bounds__(512,4) imposes).
//  - #pragma unroll 1 on the col-tile loop so the scheduler can't re-inflate
//    live ranges; 16 waves/CU (2 blocks/CU) hide ds_read latency via TLP.
//  - everything else identical to R7: 2 A-tiles/wave (1 ds_read feeds 2 MFMAs),
//    512 blocks x 128 rows, 4 col-groups merged via LDS atomicMin,
//    global_load_lds double-buffered staging.
// NOTE: fminf chains only (NO inline-asm v_min3: MFMA->VALU hazard, see R5->R6).
__global__ __launch_bounds__(TPB, 4) void main_kernel(
    const float* __restrict__ pred, const float* __restrict__ tgt,
    const int* __restrict__ edges, char* __restrict__ ws)
{
    __shared__ __align__(16) char sB[2][2 * CHUNK * 16];   // 2 x 32 KB
    __shared__ float wred[WAVES], wred2[WAVES];
    __shared__ int rowMin[ROWS_PER_BLOCK];
    double* sums = (double*)(ws + SUMS_OFF);
    const int lane = threadIdx.x & 63;
    const int wv = threadIdx.x >> 6;
    const int t = threadIdx.x;

    if (blockIdx.x < CH_BLOCKS) {
        const int dir = blockIdx.x >> 8;          // 0: rows=pred, search tgt
        const int xb = blockIdx.x & 255;
        const int batch = xb >> 7;
        const int rowInB = (xb & 127) * ROWS_PER_BLOCK;
        const float* P = dir ? tgt : pred;
        const char* fragBase = ws + (size_t)dir * DIR_FRAG_BYTES
                                  + (size_t)batch * BATCH_FRAG_BYTES;
        const int bl = lane & 31;
        const int half = lane >> 5;
        const int rp = wv & 1;                    // row-pair: tiles 2rp,2rp+1
        const int cg = wv >> 1;                   // col-group: tiles [cg*8,cg*8+8)

        auto stage = [&](int c, int buf) {
            const char* p0 = fragBase + (size_t)c * (CHUNK * 16);
            const char* p1 = fragBase + PLANE_BYTES + (size_t)c * (CHUNK * 16);
            char* d = sB[buf];
            gload_lds16(p0 + (size_t)t * 16,         d + (size_t)t * 16);
            gload_lds16(p0 + (size_t)(t + TPB) * 16, d + (size_t)(t + TPB) * 16);
            gload_lds16(p1 + (size_t)t * 16,         d + (size_t)(t + 2 * TPB) * 16);
            gload_lds16(p1 + (size_t)(t + TPB) * 16, d + (size_t)(t + 3 * TPB) * 16);
        };
        stage(0, 0);
        if (t < ROWS_PER_BLOCK) rowMin[t] = 0x7f7fffff;   // FLT_MAX bits

        // ---- A fragments for the wave's two row tiles ----
        const short one = 0x3f80;
        short8 af[2];
        #pragma unroll
        for (int j = 0; j < 2; j++) {
            int r = batch * N_SZ + rowInB + rp * 64 + j * 32 + bl;
            const float* p = P + (size_t)r * 3;
            float px = p[0], py = p[1], pz = p[2];
            float ax = -2.f * px, ay = -2.f * py, az = -2.f * pz;
            short ahx = f2bf(ax), ahy = f2bf(ay), ahz = f2bf(az);
            short alx = f2bf(ax - bf2f(ahx)), aly = f2bf(ay - bf2f(ahy)),
                  alz = f2bf(az - bf2f(ahz));
            float p2 = fmaf(px, px, fmaf(py, py, pz * pz));
            short p2h = f2bf(p2), p2l = f2bf(p2 - bf2f(p2h));
            af[j] = half == 0
                ? (short8){ahx, ahy, ahz, alx, aly, alz, p2h, p2l}
                : (short8){ahx, ahy, ahz, one, one, 0, 0, 0};
        }

        float acc0[16], acc1[16];
        #pragma unroll
        for (int e = 0; e < 16; e++) { acc0[e] = FLT_MAX; acc1[e] = FLT_MAX; }
        const f32x16 zc = {0.f, 0.f, 0.f, 0.f, 0.f, 0.f, 0.f, 0.f,
                           0.f, 0.f, 0.f, 0.f, 0.f, 0.f, 0.f, 0.f};

        __syncthreads();

        for (int c = 0; c < NCHUNK; c++) {
            int buf = c & 1;
            if (c + 1 < NCHUNK) stage(c + 1, buf ^ 1);   // async, drains at barrier
            const char* bp = sB[buf] + half * (CHUNK * 16)
                           + (size_t)(cg * TILES_PER_CG * 32 + bl) * 16;
            #pragma unroll 1
            for (int mt = 0; mt < TILES_PER_CG; mt += 2) {
                short8 b0 = *(const short8*)(bp + (mt * 32) * 16);
                short8 b1 = *(const short8*)(bp + (mt * 32 + 32) * 16);
                {   // af[0] pair -> reduce immediately (frees result regs)
                    f32x16 r0 = __builtin_amdgcn_mfma_f32_32x32x16_bf16(af[0], b0, zc, 0, 0, 0);
                    f32x16 r1 = __builtin_amdgcn_mfma_f32_32x32x16_bf16(af[0], b1, zc, 0, 0, 0);
                    #pragma unroll
                    for (int e = 0; e < 16; e++)
                        acc0[e] = fminf(fminf(r0[e], r1[e]), acc0[e]);   // v_min3-able
                }
                {   // af[1] pair reuses the same result registers
                    f32x16 r0 = __builtin_amdgcn_mfma_f32_32x32x16_bf16(af[1], b0, zc, 0, 0, 0);
                    f32x16 r1 = __builtin_amdgcn_mfma_f32_32x32x16_bf16(af[1], b1, zc, 0, 0, 0);
                    #pragma unroll
                    for (int e = 0; e < 16; e++)
                        acc1[e] = fminf(fminf(r0[e], r1[e]), acc1[e]);
                }
            }
            __syncthreads();
        }

        // ---- fold 32 col-lanes, publish per-row minima via LDS atomicMin ----
        #pragma unroll
        for (int j = 0; j < 2; j++) {
            #pragma unroll
            for (int e = 0; e < 16; e++) {
                float v = (j == 0) ? acc0[e] : acc1[e];
                v = fminf(v, __shfl_xor(v, 1));
                v = fminf(v, __shfl_xor(v, 2));
                v = fminf(v, __shfl_xor(v, 4));
                v = fminf(v, __shfl_xor(v, 8));
                v = fminf(v, __shfl_xor(v, 16));
                if (bl == 0) {
                    int row = rp * 64 + j * 32 + (e & 3) + 8 * (e >> 2) + 4 * half;
                    atomicMin(&rowMin[row], __float_as_int(fmaxf(v, 0.f)));
                }
            }
        }
        __syncthreads();

        // ---- sqrt + block sum (rows live in threads 0..127 = waves 0,1) ----
        if (t < ROWS_PER_BLOCK) {
            float s = sqrtf(__int_as_float(rowMin[t]));
            #pragma unroll
            for (int o = 32; o > 0; o >>= 1) s += __shfl_down(s, o, 64);
            if (lane == 0) wred[wv] = s;
        }
        __syncthreads();
        if (t == 0) atomicAdd(&sums[dir], (double)(wred[0] + wred[1]));
    } else {
        // ---- edge loss (int32 edges per harness convention) ----
        int idx = (blockIdx.x - CH_BLOCKS) * TPB + threadIdx.x;  // 0..98303
        int b = idx >= E_SZ;                        // block-uniform (96 blocks/b)
        int e = idx - b * E_SZ;
        int2 ee = ((const int2*)edges)[e];
        const float* p0 = pred + ((size_t)b * N_SZ + (size_t)ee.x) * 3;
        const float* p1 = pred + ((size_t)b * N_SZ + (size_t)ee.y) * 3;
        float dx = p0[0] - p1[0], dy = p0[1] - p1[1], dz = p0[2] - p1[2];
        float len = sqrtf(dx * dx + dy * dy + dz * dz);
        float s = len, q = len * len;
        for (int o = 32; o > 0; o >>= 1) {
            s += __shfl_down(s, o, 64);
            q += __shfl_down(q, o, 64);
        }
        if (lane == 0) { wred[wv] = s; wred2[wv] = q; }
        __syncthreads();
        if (threadIdx.x == 0) {
            float ts = 0.f, tq = 0.f;
            #pragma unroll
            for (int w = 0; w < WAVES; w++) { ts += wred[w]; tq += wred2[w]; }
            atomicAdd(&sums[2 + 2 * b], (double)ts);
            atomicAdd(&sums[3 + 2 * b], (double)tq);
        }
    }
}

// ---- combine to the 3 outputs ----
__global__ void final_kernel(const char* __restrict__ ws, float* __restrict__ out) {
    const double* sums = (const double*)(ws + SUMS_OFF);
    double c = sums[0] / (double)(B_SZ * N_SZ) + sums[1] / (double)(B_SZ * N_SZ);
    double e = 0.0;
    #pragma unroll
    for (int b = 0; b < B_SZ; b++) {
        double s = sums[2 + 2 * b], q = sums[3 + 2 * b];
        e += (q - s * s / (double)E_SZ) / (double)(E_SZ - 1);
    }
    e *= (1.0 / B_SZ);
    double tot = 1.0 * c + 0.1 * e;
    out[0] = (float)tot;
    out[1] = (float)c;
    out[2] = (float)e;
}

extern "C" void kernel_launch(void* const* d_in, const int* in_sizes, int n_in,
                              void* d_out, int out_size, void* d_ws, size_t ws_size,
                              hipStream_t stream) {
    const float* pred = (const float*)d_in[0];       // (B, N, 3) fp32
    const float* tgt  = (const float*)d_in[1];       // (B, M, 3) fp32
    const int* edges  = (const int*)d_in[2];         // (E, 2) int32 (harness-converted)
    float* out = (float*)d_out;
    char* ws = (char*)d_ws;                          // needs 2 MB + 48 B

    // 1) convert points to MFMA B-fragments + zero sums
    prep<<<dim3((2 * B_SZ * N_SZ) / TPB), TPB, 0, stream>>>(pred, tgt, ws);

    // 2) chamfer (512 blocks, both dirs, complete row-mins) + edge (192 blocks)
    main_kernel<<<dim3(CH_BLOCKS + EDGE_BLOCKS), TPB, 0, stream>>>(
        pred, tgt, edges, ws);

    // 3) combine
    final_kernel<<<dim3(1), dim3(1), 0, stream>>>(ws, out);
}